// Round 15
// baseline (113.487 us; speedup 1.0000x reference)
//
#include <hip/hip_runtime.h>

// Problem constants (match reference)
constexpr int NN = 100000;   // nodes
constexpr int NE = 1250000;  // edges
constexpr int D  = 64;       // in == out dim
constexpr int NB = 16;       // bases

constexpr int NC = 196;              // coarse buckets of 512 nodes (99999>>9 = 195)
constexpr int PA_BLOCKS = 512;       // pass-A blocks (per-block private regions)
constexpr int NCB = NC * PA_BLOCKS;  // 100352 (bucket-major counters)
constexpr int NSBLK = (NCB + 255) / 256;   // 392 scan blocks
constexpr int EPB = (NE + PA_BLOCKS - 1) / PA_BLOCKS;  // 2442 edges per block

typedef __attribute__((ext_vector_type(8))) short short8v;   // 8 bf16 (4 VGPR)
typedef __attribute__((ext_vector_type(4))) float float4v;

__device__ __forceinline__ unsigned short f2bf(float f) {
    unsigned u = __float_as_uint(f);
    u += 0x7fffu + ((u >> 16) & 1u);     // round-to-nearest-even
    return (unsigned short)(u >> 16);
}

// ---------------------------------------------------------------------------
// Kernel 1 (merged): blocks [0,PA_BLOCKS) = per-block coarse histogram;
// blocks beyond = combine bases -> WcT(bf16),B | zero scan flags | cast x->bf16.
// WcT layout: [o][k] bf16, k = i for W_msg (k<64), k = 64+i for W_self.
// ---------------------------------------------------------------------------
constexpr int PRE_COMBINE = 8192 + 128;                 // 8320
constexpr int PRE_FLAGS   = PRE_COMBINE + NSBLK;        // + scan-flag zeroing
constexpr int PRE_TOTAL   = PRE_FLAGS + NN * (D / 4);   // + cast tasks
constexpr int PREP_GRID   = PA_BLOCKS + (PRE_TOTAL + 255) / 256;

__global__ void prep_kernel(const float* __restrict__ wm,
                            const float* __restrict__ bm,
                            const float* __restrict__ wsf,
                            const float* __restrict__ bsf,
                            const float* __restrict__ lc,
                            const float* __restrict__ x,
                            const int* __restrict__ ei,
                            int* __restrict__ bhist,
                            unsigned short* __restrict__ wct, // [64*128] bf16
                            float* __restrict__ B,            // [128] fp32
                            int* __restrict__ bflag,          // [NSBLK] scan flags
                            unsigned short* __restrict__ xb)
{
    __shared__ int h[NC];
    const int tid = threadIdx.x;

    if (blockIdx.x < PA_BLOCKS) {
        // ---- coarse histogram over this block's edge range ----
        if (tid < NC) h[tid] = 0;
        __syncthreads();
        const int begin = blockIdx.x * EPB;
        const int end = min(NE, begin + EPB);
        for (int e = begin + tid; e < end; e += 256)
            atomicAdd(&h[ei[NE + e] >> 9], 1);
        __syncthreads();
        if (tid < NC) bhist[tid * PA_BLOCKS + blockIdx.x] = h[tid];
        return;
    }

    int t = (blockIdx.x - PA_BLOCKS) * 256 + tid;
    if (t < PRE_COMBINE) {
        float c[NB];
        #pragma unroll
        for (int b = 0; b < NB; ++b) c[b] = lc[b];
        const float* p;
        if (t < 4096)      p = wm  + t * NB;
        else if (t < 8192) p = wsf + (t - 4096) * NB;
        else if (t < 8256) p = bm  + (t - 8192) * NB;
        else               p = bsf + (t - 8256) * NB;
        float s = 0.f;
        #pragma unroll
        for (int b = 0; b < NB; ++b) s += p[b] * c[b];

        if (t < 4096) {                       // W_msg[i][o] -> wct[o][i]
            int i = t >> 6, o = t & 63;
            wct[o * 128 + i] = f2bf(s);
        } else if (t < 8192) {                // W_self[i][o] -> wct[o][64+i]
            int u = t - 4096;
            int i = u >> 6, o = u & 63;
            wct[o * 128 + 64 + i] = f2bf(s);
        } else if (t < 8256) {
            B[t - 8192] = s;                  // b_msg
        } else {
            B[64 + (t - 8256)] = s;           // b_self
        }
    } else if (t < PRE_FLAGS) {
        bflag[t - PRE_COMBINE] = 0;           // re-zeroed every call (replay-safe)
    } else if (t < PRE_TOTAL) {
        int k = t - PRE_FLAGS;                // [0, NN*16)
        float4 v = reinterpret_cast<const float4*>(x)[k];
        ushort4 o;
        o.x = f2bf(v.x); o.y = f2bf(v.y); o.z = f2bf(v.z); o.w = f2bf(v.w);
        reinterpret_cast<ushort4*>(xb)[k] = o;
    }
}

// ---------------------------------------------------------------------------
// Kernel 2: fused single-pass exclusive scan over NCB counters.
// Each block: local scan, publish aggregate (release), poll-and-sum all
// predecessor aggregates (acquire). 392 blocks << 2048 co-resident capacity
// -> all blocks run concurrently, no deadlock regardless of dispatch order.
// ---------------------------------------------------------------------------
__global__ __launch_bounds__(256)
void scan_fused(int* __restrict__ data,
                int* __restrict__ bsum,
                int* __restrict__ bflag, int n)
{
    __shared__ int tmp[256];
    const int b = blockIdx.x;
    const int tid = threadIdx.x;
    const int i = b * 256 + tid;

    int c = (i < n) ? data[i] : 0;
    int v = c;
    tmp[tid] = v;
    __syncthreads();
    for (int d = 1; d < 256; d <<= 1) {
        int t = (tid >= d) ? tmp[tid - d] : 0;
        __syncthreads();
        v += t;
        tmp[tid] = v;
        __syncthreads();
    }

    // publish this block's aggregate (tmp[255] == block total)
    if (tid == 255) {
        __hip_atomic_store(&bsum[b], v, __ATOMIC_RELEASE, __HIP_MEMORY_SCOPE_AGENT);
        __hip_atomic_store(&bflag[b], 1, __ATOMIC_RELEASE, __HIP_MEMORY_SCOPE_AGENT);
    }

    // poll-and-sum predecessors
    int s = 0;
    for (int k = tid; k < b; k += 256) {
        while (__hip_atomic_load(&bflag[k], __ATOMIC_ACQUIRE, __HIP_MEMORY_SCOPE_AGENT) == 0) {}
        s += __hip_atomic_load(&bsum[k], __ATOMIC_RELAXED, __HIP_MEMORY_SCOPE_AGENT);
    }
    __syncthreads();                 // tmp free for reuse
    tmp[tid] = s;
    __syncthreads();
    for (int d = 128; d; d >>= 1) {
        if (tid < d) tmp[tid] += tmp[tid + d];
        __syncthreads();
    }
    if (i < n) data[i] = v - c + tmp[0];
}

// ---------------------------------------------------------------------------
// Kernel 3 (pass A): scatter into per-(bucket,block) private regions.
// No global atomics, no barriers in the hot loop. Payload (src<<9)|(dst&511).
// ---------------------------------------------------------------------------
__global__ __launch_bounds__(256)
void passA_scatter(const int* __restrict__ ei,
                   const int* __restrict__ starts,   // scanned bhist
                   int* __restrict__ pair_buf)
{
    __shared__ int cnt[NC];
    __shared__ int base[NC];
    const int tid = threadIdx.x;
    for (int j = tid; j < NC; j += 256) {
        cnt[j] = 0;
        base[j] = starts[j * PA_BLOCKS + blockIdx.x];
    }
    __syncthreads();

    const int begin = blockIdx.x * EPB;
    const int end = min(NE, begin + EPB);
    for (int e = begin + tid; e < end; e += 256) {
        int src = ei[e];
        int dst = ei[NE + e];
        int key = dst >> 9;
        int pos = base[key] + atomicAdd(&cnt[key], 1);   // LDS atomic only
        pair_buf[pos] = (src << 9) | (dst & 511);
    }
}

// ---------------------------------------------------------------------------
// Kernel 4 (pass B): per coarse bucket, sort entries to node order inside the
// bucket's own contiguous window (L2-local); emit counts + node_start.
// ---------------------------------------------------------------------------
__global__ __launch_bounds__(512)
void passB_sort(const int* __restrict__ pair_buf,
                const int* __restrict__ starts,      // scanned bhist
                int* __restrict__ sorted_src,
                int* __restrict__ node_start,
                int* __restrict__ counts)
{
    __shared__ int tmp[512];
    __shared__ int cur[512];
    const int b = blockIdx.x;
    const int s = starts[b * PA_BLOCKS];
    const int e = (b == NC - 1) ? NE : starts[(b + 1) * PA_BLOCKS];
    const int tid = threadIdx.x;

    tmp[tid] = 0;
    __syncthreads();
    for (int i = s + tid; i < e; i += 512)
        atomicAdd(&tmp[pair_buf[i] & 511], 1);       // LDS node hist
    __syncthreads();

    // block-wide exclusive scan over 512
    int c0 = tmp[tid];
    int v = c0;
    __syncthreads();
    tmp[tid] = v;
    __syncthreads();
    for (int d = 1; d < 512; d <<= 1) {
        int t = (tid >= d) ? tmp[tid - d] : 0;
        __syncthreads();
        v += t;
        tmp[tid] = v;
        __syncthreads();
    }
    int excl = v - c0;

    const int n = (b << 9) + tid;
    if (n < NN) {
        counts[n] = c0;
        node_start[n] = s + excl;
    }
    cur[tid] = excl;
    __syncthreads();

    for (int i = s + tid; i < e; i += 512) {
        int w = pair_buf[i];
        int pos = atomicAdd(&cur[w & 511], 1);       // LDS rank
        sorted_src[s + pos] = w >> 9;                // write in own window
    }
}

// ---------------------------------------------------------------------------
// Kernel 5: gather-sum bf16 x rows -> packed-bf16 agg rows (aggb, ws).
// TWO nodes per wave, software-pipelined: both nodes' metadata and index
// vectors are loaded up front (independent, all in flight together), then
// the two nodes are processed back-to-back (r13 pair-edge body: bpermute
// broadcast, 32-bit saddr, 2-shuffle reduce).
// ---------------------------------------------------------------------------
__global__ __launch_bounds__(256)
void gather_kernel(const unsigned int* __restrict__ xbd,  // xb as dwords [NN*32]
                   const int* __restrict__ sorted_src,
                   const int* __restrict__ node_start,
                   const int* __restrict__ counts,
                   unsigned int* __restrict__ aggb)       // bf16x2 dwords [NN*32]
{
    const int wave = threadIdx.x >> 6;
    const int lane = threadIdx.x & 63;
    const int half = lane >> 5;          // edge parity slot
    const int dq   = lane & 31;          // dword within row
    const int n0 = blockIdx.x * 8 + wave * 2;   // 12500 * 8 == NN exactly
    const int n1 = n0 + 1;

    // pipelined prologue: both nodes' metadata + index vectors in flight
    const int deg0 = counts[n0];
    const int deg1 = counts[n1];
    const int s0 = node_start[n0];
    const int s1 = node_start[n1];
    int idx0 = 0, idx1 = 0;
    if (lane < deg0) idx0 = sorted_src[s0 + lane];
    if (lane < deg1) idx1 = sorted_src[s1 + lane];

    #pragma unroll
    for (int nn = 0; nn < 2; ++nn) {
        const int deg  = nn ? deg1 : deg0;
        const int j0   = nn ? s1 : s0;
        const int idxv = nn ? idx1 : idx0;
        const int n    = nn ? n1 : n0;

        float aL[8], aH[8];
        #pragma unroll
        for (int p = 0; p < 8; ++p) { aL[p] = 0.f; aH[p] = 0.f; }

        const int dmain = min(deg, 64);
        for (int jj = 0; jj < dmain; jj += 16) {
            #pragma unroll
            for (int p = 0; p < 8; ++p) {
                int pos = jj + 2 * p + half;
                int srcl = __builtin_amdgcn_ds_bpermute(pos << 2, idxv);
                unsigned int u = xbd[(((unsigned)srcl) << 5) | (unsigned)dq];
                u = (pos < dmain) ? u : 0u;          // cndmask, no exec toggle
                aL[p] += __uint_as_float(u << 16);
                aH[p] += __uint_as_float(u & 0xffff0000u);
            }
        }
        // rare tail: deg > 64
        for (int pos = 64 + half; pos < deg; pos += 2) {
            int srcl = sorted_src[j0 + pos];
            unsigned int u = xbd[(((unsigned)srcl) << 5) | (unsigned)dq];
            aL[0] += __uint_as_float(u << 16);
            aH[0] += __uint_as_float(u & 0xffff0000u);
        }

        float sL = ((aL[0] + aL[1]) + (aL[2] + aL[3])) + ((aL[4] + aL[5]) + (aL[6] + aL[7]));
        float sH = ((aH[0] + aH[1]) + (aH[2] + aH[3])) + ((aH[4] + aH[5]) + (aH[6] + aH[7]));

        sL += __shfl_xor(sL, 32, 64);
        sH += __shfl_xor(sH, 32, 64);

        if (half == 0) {
            unsigned pk = ((unsigned)f2bf(sH) << 16) | (unsigned)f2bf(sL);
            aggb[(((unsigned)n) << 5) | (unsigned)dq] = pk;
        }
    }
}

// ---------------------------------------------------------------------------
// Kernel 6: MFMA transform + normalize. A = [aggb | xb] bf16 (direct frags).
// A-frag: lane row = l&15, k = (l>>4)*8+j.  B-frag: col o = l&15, same k.
// C/D: col = l&15, row = (l>>4)*4 + reg  [m89 verified layout]
// ---------------------------------------------------------------------------
constexpr int NTILES = NN / 16;          // 6250
constexpr int TBLOCKS = 640;             // persistent blocks (2560 waves)

__global__ __launch_bounds__(256)
void transform_mfma(float* __restrict__ out,
                    const unsigned short* __restrict__ aggb, // [NN][64] bf16
                    const unsigned short* __restrict__ xb,   // [NN][64] bf16
                    const unsigned short* __restrict__ wct,  // [64][128] bf16
                    const float* __restrict__ B,             // [128] fp32
                    const int* __restrict__ counts)
{
    const int lane = threadIdx.x & 63;
    const int gq = lane >> 4;        // 0..3
    const int c  = lane & 15;
    const int wglob = blockIdx.x * 4 + (threadIdx.x >> 6);

    // Hoist W fragments: wf[otile][ks] — 64 VGPRs
    short8v wf[4][4];
    #pragma unroll
    for (int t = 0; t < 4; ++t)
        #pragma unroll
        for (int ks = 0; ks < 4; ++ks) {
            int o = t * 16 + c;
            int k0 = ks * 32 + gq * 8;
            wf[t][ks] = *reinterpret_cast<const short8v*>(wct + o * 128 + k0);
        }
    // Hoist biases (per-lane o columns)
    float bmv[4], bsv[4];
    #pragma unroll
    for (int t = 0; t < 4; ++t) {
        bmv[t] = B[t * 16 + c];
        bsv[t] = B[64 + t * 16 + c];
    }

    for (int tile = wglob; tile < NTILES; tile += TBLOCKS * 4) {
        const int n0 = tile * 16;
        const size_t arow = (size_t)(n0 + c) * D;   // this lane's A row

        float4v acc[4];
        #pragma unroll
        for (int t = 0; t < 4; ++t) acc[t] = (float4v){0.f, 0.f, 0.f, 0.f};

        // ks = 0,1 : agg (bf16, direct)
        #pragma unroll
        for (int ks = 0; ks < 2; ++ks) {
            short8v a = *reinterpret_cast<const short8v*>(aggb + arow + ks * 32 + gq * 8);
            #pragma unroll
            for (int t = 0; t < 4; ++t)
                acc[t] = __builtin_amdgcn_mfma_f32_16x16x32_bf16(a, wf[t][ks], acc[t], 0, 0, 0);
        }
        // ks = 2,3 : x (bf16, direct)
        #pragma unroll
        for (int ks = 2; ks < 4; ++ks) {
            short8v a = *reinterpret_cast<const short8v*>(xb + arow + (ks - 2) * 32 + gq * 8);
            #pragma unroll
            for (int t = 0; t < 4; ++t)
                acc[t] = __builtin_amdgcn_mfma_f32_16x16x32_bf16(a, wf[t][ks], acc[t], 0, 0, 0);
        }

        // epilogue: bias + deg*b_msg, row L2-norm, write
        float dg[4];
        #pragma unroll
        for (int q = 0; q < 4; ++q) dg[q] = (float)counts[n0 + gq * 4 + q];

        float ss[4] = {0.f, 0.f, 0.f, 0.f};
        #pragma unroll
        for (int t = 0; t < 4; ++t)
            #pragma unroll
            for (int q = 0; q < 4; ++q) {
                float v = acc[t][q] + dg[q] * bmv[t] + bsv[t];
                acc[t][q] = v;
                ss[q] += v * v;
            }
        #pragma unroll
        for (int off = 1; off <= 8; off <<= 1)
            #pragma unroll
            for (int q = 0; q < 4; ++q) ss[q] += __shfl_xor(ss[q], off, 64);

        float sc[4];
        #pragma unroll
        for (int q = 0; q < 4; ++q) sc[q] = 1.f / fmaxf(sqrtf(ss[q]), 1e-12f);

        #pragma unroll
        for (int t = 0; t < 4; ++t)
            #pragma unroll
            for (int q = 0; q < 4; ++q)
                out[(size_t)(n0 + gq * 4 + q) * D + t * 16 + c] = acc[t][q] * sc[q];
    }
}

// ---------------------------------------------------------------------------
extern "C" void kernel_launch(void* const* d_in, const int* in_sizes, int n_in,
                              void* d_out, int out_size, void* d_ws, size_t ws_size,
                              hipStream_t stream)
{
    const float* x   = (const float*)d_in[0];
    const int*   ei  = (const int*)d_in[1];
    const float* wm  = (const float*)d_in[2];
    const float* bm  = (const float*)d_in[3];
    const float* wsf = (const float*)d_in[4];
    const float* bsf = (const float*)d_in[5];
    const float* lc  = (const float*)d_in[6];

    float* out = (float*)d_out;

    // ws layout (4B words). xb/aggb LAST so any overrun lands in dead space.
    // B[128] | wct[4096w] | bhist/starts[NCB] | bsum[512] | bflag[512]
    //   | counts[NN] | node_start[NN] | pair_buf[NE] | sorted_src[NE]
    //   | xb[NN*32w] | aggb[NN*32w]
    float* Bv         = (float*)d_ws;
    unsigned short* wct = (unsigned short*)(Bv + 128);
    int* starts       = (int*)(wct + 8192);
    int* bsum         = starts + NCB;
    int* bflag        = bsum + 512;
    int* counts       = bflag + 512;
    int* node_start   = counts + NN;
    int* pair_buf     = node_start + NN;
    int* sorted_src   = pair_buf + NE;
    unsigned short* xb   = (unsigned short*)(sorted_src + NE);
    unsigned int*   aggb = (unsigned int*)(xb + (size_t)NN * D);

    // 1. merged: per-block coarse hist | combine bases | zero flags | cast x->bf16
    prep_kernel<<<PREP_GRID, 256, 0, stream>>>(
        wm, bm, wsf, bsf, lc, x, ei, starts, wct, Bv, bflag, xb);

    // 2. fused single-pass exclusive scan of NCB counters (in place)
    scan_fused<<<NSBLK, 256, 0, stream>>>(starts, bsum, bflag, NCB);

    // 3. pass A: scatter to per-(bucket,block) private regions
    passA_scatter<<<PA_BLOCKS, 256, 0, stream>>>(ei, starts, pair_buf);

    // 4. pass B: per-bucket node sort + counts + node_start
    passB_sort<<<NC, 512, 0, stream>>>(pair_buf, starts,
                                       sorted_src, node_start, counts);

    // 5. gather-sum bf16 rows -> packed bf16 agg (ws), 2 nodes/wave pipelined
    gather_kernel<<<NN / 8, 256, 0, stream>>>(
        (const unsigned int*)xb, sorted_src, node_start, counts, aggb);

    // 6. MFMA transform + normalize (aggb,xb -> out)
    transform_mfma<<<TBLOCKS, 256, 0, stream>>>(
        out, (const unsigned short*)aggb, xb, wct, Bv, counts);
}

// Round 16
// 84.387 us; speedup vs baseline: 1.3448x; 1.3448x over previous
//
#include <hip/hip_runtime.h>

// Problem constants (match reference)
constexpr int NN = 100000;   // nodes
constexpr int NE = 1250000;  // edges
constexpr int D  = 64;       // in == out dim
constexpr int NB = 16;       // bases

constexpr int NC = 196;              // coarse buckets of 512 nodes (99999>>9 = 195)
constexpr int PA_BLOCKS = 512;       // pass-A blocks (per-block private regions)
constexpr int NCB = NC * PA_BLOCKS;  // 100352 (bucket-major counters)
constexpr int NSBLK = (NCB + 255) / 256;   // 392 scan blocks
constexpr int EPB = (NE + PA_BLOCKS - 1) / PA_BLOCKS;  // 2442 edges per block

typedef __attribute__((ext_vector_type(8))) short short8v;   // 8 bf16 (4 VGPR)
typedef __attribute__((ext_vector_type(4))) float float4v;

__device__ __forceinline__ unsigned short f2bf(float f) {
    unsigned u = __float_as_uint(f);
    u += 0x7fffu + ((u >> 16) & 1u);     // round-to-nearest-even
    return (unsigned short)(u >> 16);
}

// ---------------------------------------------------------------------------
// Kernel 1 (merged): blocks [0,PA_BLOCKS) = per-block coarse histogram;
// blocks beyond = combine bases -> WcT(bf16),B | cast x -> bf16.
// WcT layout: [o][k] bf16, k = i for W_msg (k<64), k = 64+i for W_self.
// ---------------------------------------------------------------------------
constexpr int PRE_COMBINE = 8192 + 128;                 // 8320
constexpr int PRE_TOTAL   = PRE_COMBINE + NN * (D / 4); // + cast tasks
constexpr int PREP_GRID   = PA_BLOCKS + (PRE_TOTAL + 255) / 256;

__global__ void prep_kernel(const float* __restrict__ wm,
                            const float* __restrict__ bm,
                            const float* __restrict__ wsf,
                            const float* __restrict__ bsf,
                            const float* __restrict__ lc,
                            const float* __restrict__ x,
                            const int* __restrict__ ei,
                            int* __restrict__ bhist,
                            unsigned short* __restrict__ wct, // [64*128] bf16
                            float* __restrict__ B,            // [128] fp32
                            unsigned short* __restrict__ xb)
{
    __shared__ int h[NC];
    const int tid = threadIdx.x;

    if (blockIdx.x < PA_BLOCKS) {
        // ---- coarse histogram over this block's edge range ----
        if (tid < NC) h[tid] = 0;
        __syncthreads();
        const int begin = blockIdx.x * EPB;
        const int end = min(NE, begin + EPB);
        for (int e = begin + tid; e < end; e += 256)
            atomicAdd(&h[ei[NE + e] >> 9], 1);
        __syncthreads();
        if (tid < NC) bhist[tid * PA_BLOCKS + blockIdx.x] = h[tid];
        return;
    }

    int t = (blockIdx.x - PA_BLOCKS) * 256 + tid;
    if (t < PRE_COMBINE) {
        float c[NB];
        #pragma unroll
        for (int b = 0; b < NB; ++b) c[b] = lc[b];
        const float* p;
        if (t < 4096)      p = wm  + t * NB;
        else if (t < 8192) p = wsf + (t - 4096) * NB;
        else if (t < 8256) p = bm  + (t - 8192) * NB;
        else               p = bsf + (t - 8256) * NB;
        float s = 0.f;
        #pragma unroll
        for (int b = 0; b < NB; ++b) s += p[b] * c[b];

        if (t < 4096) {                       // W_msg[i][o] -> wct[o][i]
            int i = t >> 6, o = t & 63;
            wct[o * 128 + i] = f2bf(s);
        } else if (t < 8192) {                // W_self[i][o] -> wct[o][64+i]
            int u = t - 4096;
            int i = u >> 6, o = u & 63;
            wct[o * 128 + 64 + i] = f2bf(s);
        } else if (t < 8256) {
            B[t - 8192] = s;                  // b_msg
        } else {
            B[64 + (t - 8256)] = s;           // b_self
        }
    } else if (t < PRE_TOTAL) {
        int k = t - PRE_COMBINE;              // [0, NN*16)
        float4 v = reinterpret_cast<const float4*>(x)[k];
        ushort4 o;
        o.x = f2bf(v.x); o.y = f2bf(v.y); o.z = f2bf(v.z); o.w = f2bf(v.w);
        reinterpret_cast<ushort4*>(xb)[k] = o;
    }
}

// ---------------------------------------------------------------------------
// Kernels 2a/2b: exclusive scan (in place) over NCB counters.
// ---------------------------------------------------------------------------
__global__ void scan_block(int* __restrict__ data,
                           int* __restrict__ partials, int n)
{
    __shared__ int tmp[256];
    int tid = threadIdx.x;
    int i = blockIdx.x * 256 + tid;
    int c = (i < n) ? data[i] : 0;
    int v = c;
    tmp[tid] = v;
    __syncthreads();
    for (int d = 1; d < 256; d <<= 1) {
        int t = (tid >= d) ? tmp[tid - d] : 0;
        __syncthreads();
        v += t;
        tmp[tid] = v;
        __syncthreads();
    }
    if (i < n) data[i] = v - c;
    if (tid == 255) partials[blockIdx.x] = v;
}

__global__ void add_offsets(int* __restrict__ data,
                            const int* __restrict__ partials, int n)
{
    __shared__ int red[256];
    const int tid = threadIdx.x;
    int s = 0;
    for (int i = tid; i < blockIdx.x; i += 256) s += partials[i];
    red[tid] = s;
    __syncthreads();
    for (int d = 128; d; d >>= 1) {
        if (tid < d) red[tid] += red[tid + d];
        __syncthreads();
    }
    int i = blockIdx.x * 256 + tid;
    if (i < n) data[i] += red[0];
}

// ---------------------------------------------------------------------------
// Kernel 3 (pass A): scatter into per-(bucket,block) private regions.
// No global atomics, no barriers in the hot loop. Payload (src<<9)|(dst&511).
// ---------------------------------------------------------------------------
__global__ __launch_bounds__(256)
void passA_scatter(const int* __restrict__ ei,
                   const int* __restrict__ starts,   // scanned bhist
                   int* __restrict__ pair_buf)
{
    __shared__ int cnt[NC];
    __shared__ int base[NC];
    const int tid = threadIdx.x;
    for (int j = tid; j < NC; j += 256) {
        cnt[j] = 0;
        base[j] = starts[j * PA_BLOCKS + blockIdx.x];
    }
    __syncthreads();

    const int begin = blockIdx.x * EPB;
    const int end = min(NE, begin + EPB);
    for (int e = begin + tid; e < end; e += 256) {
        int src = ei[e];
        int dst = ei[NE + e];
        int key = dst >> 9;
        int pos = base[key] + atomicAdd(&cnt[key], 1);   // LDS atomic only
        pair_buf[pos] = (src << 9) | (dst & 511);
    }
}

// ---------------------------------------------------------------------------
// Kernel 4 (pass B): per coarse bucket, sort entries to node order inside the
// bucket's own contiguous window (L2-local); emit meta = {node_start, deg}.
// ---------------------------------------------------------------------------
__global__ __launch_bounds__(512)
void passB_sort(const int* __restrict__ pair_buf,
                const int* __restrict__ starts,      // scanned bhist
                int* __restrict__ sorted_src,
                int2* __restrict__ meta)             // [NN] {start, deg}
{
    __shared__ int tmp[512];
    __shared__ int cur[512];
    const int b = blockIdx.x;
    const int s = starts[b * PA_BLOCKS];
    const int e = (b == NC - 1) ? NE : starts[(b + 1) * PA_BLOCKS];
    const int tid = threadIdx.x;

    tmp[tid] = 0;
    __syncthreads();
    for (int i = s + tid; i < e; i += 512)
        atomicAdd(&tmp[pair_buf[i] & 511], 1);       // LDS node hist
    __syncthreads();

    // block-wide exclusive scan over 512
    int c0 = tmp[tid];
    int v = c0;
    __syncthreads();
    tmp[tid] = v;
    __syncthreads();
    for (int d = 1; d < 512; d <<= 1) {
        int t = (tid >= d) ? tmp[tid - d] : 0;
        __syncthreads();
        v += t;
        tmp[tid] = v;
        __syncthreads();
    }
    int excl = v - c0;

    const int n = (b << 9) + tid;
    if (n < NN) meta[n] = make_int2(s + excl, c0);
    cur[tid] = excl;
    __syncthreads();

    for (int i = s + tid; i < e; i += 512) {
        int w = pair_buf[i];
        int pos = atomicAdd(&cur[w & 511], 1);       // LDS rank
        sorted_src[s + pos] = w >> 9;                // write in own window
    }
}

// ---------------------------------------------------------------------------
// Kernel 5: gather-sum bf16 x rows -> packed-bf16 agg rows (aggb, ws).
// One wave per node (TLP is the latency hider — r12/r15 lesson: do NOT
// consolidate nodes per wave). Single int2 meta load shortens the serial
// prologue chain: meta -> idxv -> bpermute -> row loads.
// ---------------------------------------------------------------------------
__global__ __launch_bounds__(256)
void gather_kernel(const unsigned int* __restrict__ xbd,  // xb as dwords [NN*32]
                   const int* __restrict__ sorted_src,
                   const int2* __restrict__ meta,         // {start, deg}
                   unsigned int* __restrict__ aggb)       // bf16x2 dwords [NN*32]
{
    const int wave = threadIdx.x >> 6;
    const int lane = threadIdx.x & 63;
    const int half = lane >> 5;          // edge parity slot
    const int dq   = lane & 31;          // dword within row
    const int n = blockIdx.x * 4 + wave; // 25000 * 4 == NN exactly

    const int2 md = meta[n];             // one dwordx2 load
    const int j0 = md.x;
    const int deg = md.y;

    // one vector load of this node's first <=64 edge indices (0 when unused)
    int idxv = 0;
    if (lane < deg) idxv = sorted_src[j0 + lane];

    float aL[8], aH[8];
    #pragma unroll
    for (int p = 0; p < 8; ++p) { aL[p] = 0.f; aH[p] = 0.f; }

    const int dmain = min(deg, 64);
    for (int jj = 0; jj < dmain; jj += 16) {
        #pragma unroll
        for (int p = 0; p < 8; ++p) {
            int pos = jj + 2 * p + half;
            int srcl = __builtin_amdgcn_ds_bpermute(pos << 2, idxv);
            unsigned int u = xbd[(((unsigned)srcl) << 5) | (unsigned)dq];
            u = (pos < dmain) ? u : 0u;          // cndmask, no exec toggle
            aL[p] += __uint_as_float(u << 16);
            aH[p] += __uint_as_float(u & 0xffff0000u);
        }
    }
    // rare tail: deg > 64
    for (int pos = 64 + half; pos < deg; pos += 2) {
        int srcl = sorted_src[j0 + pos];
        unsigned int u = xbd[(((unsigned)srcl) << 5) | (unsigned)dq];
        aL[0] += __uint_as_float(u << 16);
        aH[0] += __uint_as_float(u & 0xffff0000u);
    }

    float sL = ((aL[0] + aL[1]) + (aL[2] + aL[3])) + ((aL[4] + aL[5]) + (aL[6] + aL[7]));
    float sH = ((aH[0] + aH[1]) + (aH[2] + aH[3])) + ((aH[4] + aH[5]) + (aH[6] + aH[7]));

    // combine even-edge (lanes 0-31) and odd-edge (lanes 32-63) partials
    sL += __shfl_xor(sL, 32, 64);
    sH += __shfl_xor(sH, 32, 64);

    if (half == 0) {
        // dims 2dq (lo) | 2dq+1 (hi) -> packed bf16 dword, 128B/row coalesced
        unsigned pk = ((unsigned)f2bf(sH) << 16) | (unsigned)f2bf(sL);
        aggb[(((unsigned)n) << 5) | (unsigned)dq] = pk;
    }
}

// ---------------------------------------------------------------------------
// Kernel 6: MFMA transform + normalize. A = [aggb | xb] bf16 (direct frags).
// A-frag: lane row = l&15, k = (l>>4)*8+j.  B-frag: col o = l&15, same k.
// C/D: col = l&15, row = (l>>4)*4 + reg  [m89 verified layout]
// ---------------------------------------------------------------------------
constexpr int NTILES = NN / 16;          // 6250
constexpr int TBLOCKS = 640;             // persistent blocks (2560 waves)

__global__ __launch_bounds__(256)
void transform_mfma(float* __restrict__ out,
                    const unsigned short* __restrict__ aggb, // [NN][64] bf16
                    const unsigned short* __restrict__ xb,   // [NN][64] bf16
                    const unsigned short* __restrict__ wct,  // [64][128] bf16
                    const float* __restrict__ B,             // [128] fp32
                    const int2* __restrict__ meta)           // {start, deg}
{
    const int lane = threadIdx.x & 63;
    const int gq = lane >> 4;        // 0..3
    const int c  = lane & 15;
    const int wglob = blockIdx.x * 4 + (threadIdx.x >> 6);

    // Hoist W fragments: wf[otile][ks] — 64 VGPRs
    short8v wf[4][4];
    #pragma unroll
    for (int t = 0; t < 4; ++t)
        #pragma unroll
        for (int ks = 0; ks < 4; ++ks) {
            int o = t * 16 + c;
            int k0 = ks * 32 + gq * 8;
            wf[t][ks] = *reinterpret_cast<const short8v*>(wct + o * 128 + k0);
        }
    // Hoist biases (per-lane o columns)
    float bmv[4], bsv[4];
    #pragma unroll
    for (int t = 0; t < 4; ++t) {
        bmv[t] = B[t * 16 + c];
        bsv[t] = B[64 + t * 16 + c];
    }

    for (int tile = wglob; tile < NTILES; tile += TBLOCKS * 4) {
        const int n0 = tile * 16;
        const size_t arow = (size_t)(n0 + c) * D;   // this lane's A row

        float4v acc[4];
        #pragma unroll
        for (int t = 0; t < 4; ++t) acc[t] = (float4v){0.f, 0.f, 0.f, 0.f};

        // ks = 0,1 : agg (bf16, direct)
        #pragma unroll
        for (int ks = 0; ks < 2; ++ks) {
            short8v a = *reinterpret_cast<const short8v*>(aggb + arow + ks * 32 + gq * 8);
            #pragma unroll
            for (int t = 0; t < 4; ++t)
                acc[t] = __builtin_amdgcn_mfma_f32_16x16x32_bf16(a, wf[t][ks], acc[t], 0, 0, 0);
        }
        // ks = 2,3 : x (bf16, direct)
        #pragma unroll
        for (int ks = 2; ks < 4; ++ks) {
            short8v a = *reinterpret_cast<const short8v*>(xb + arow + (ks - 2) * 32 + gq * 8);
            #pragma unroll
            for (int t = 0; t < 4; ++t)
                acc[t] = __builtin_amdgcn_mfma_f32_16x16x32_bf16(a, wf[t][ks], acc[t], 0, 0, 0);
        }

        // epilogue: bias + deg*b_msg, row L2-norm, write
        float dg[4];
        #pragma unroll
        for (int q = 0; q < 4; ++q) dg[q] = (float)meta[n0 + gq * 4 + q].y;

        float ss[4] = {0.f, 0.f, 0.f, 0.f};
        #pragma unroll
        for (int t = 0; t < 4; ++t)
            #pragma unroll
            for (int q = 0; q < 4; ++q) {
                float v = acc[t][q] + dg[q] * bmv[t] + bsv[t];
                acc[t][q] = v;
                ss[q] += v * v;
            }
        #pragma unroll
        for (int off = 1; off <= 8; off <<= 1)
            #pragma unroll
            for (int q = 0; q < 4; ++q) ss[q] += __shfl_xor(ss[q], off, 64);

        float sc[4];
        #pragma unroll
        for (int q = 0; q < 4; ++q) sc[q] = 1.f / fmaxf(sqrtf(ss[q]), 1e-12f);

        #pragma unroll
        for (int t = 0; t < 4; ++t)
            #pragma unroll
            for (int q = 0; q < 4; ++q)
                out[(size_t)(n0 + gq * 4 + q) * D + t * 16 + c] = acc[t][q] * sc[q];
    }
}

// ---------------------------------------------------------------------------
extern "C" void kernel_launch(void* const* d_in, const int* in_sizes, int n_in,
                              void* d_out, int out_size, void* d_ws, size_t ws_size,
                              hipStream_t stream)
{
    const float* x   = (const float*)d_in[0];
    const int*   ei  = (const int*)d_in[1];
    const float* wm  = (const float*)d_in[2];
    const float* bm  = (const float*)d_in[3];
    const float* wsf = (const float*)d_in[4];
    const float* bsf = (const float*)d_in[5];
    const float* lc  = (const float*)d_in[6];

    float* out = (float*)d_out;

    // ws layout (4B words). xb/aggb LAST so any overrun lands in dead space.
    // B[128] | wct[4096w] | bhist/starts[NCB] | partials[512]
    //   | meta[2*NN] | pair_buf[NE] | sorted_src[NE] | xb[NN*32w] | aggb[NN*32w]
    float* Bv         = (float*)d_ws;
    unsigned short* wct = (unsigned short*)(Bv + 128);
    int* starts       = (int*)(wct + 8192);
    int* partials     = starts + NCB;
    int2* meta        = (int2*)(partials + 512);     // 8B-aligned (even word offset)
    int* pair_buf     = (int*)(meta + NN);
    int* sorted_src   = pair_buf + NE;
    unsigned short* xb   = (unsigned short*)(sorted_src + NE);
    unsigned int*   aggb = (unsigned int*)(xb + (size_t)NN * D);

    // 1. merged: per-block coarse hist | combine bases | cast x->bf16
    prep_kernel<<<PREP_GRID, 256, 0, stream>>>(
        wm, bm, wsf, bsf, lc, x, ei, starts, wct, Bv, xb);

    // 2. exclusive scan of NCB counters (in place)
    scan_block<<<NSBLK, 256, 0, stream>>>(starts, partials, NCB);
    add_offsets<<<NSBLK, 256, 0, stream>>>(starts, partials, NCB);

    // 3. pass A: scatter to per-(bucket,block) private regions
    passA_scatter<<<PA_BLOCKS, 256, 0, stream>>>(ei, starts, pair_buf);

    // 4. pass B: per-bucket node sort -> sorted_src + meta{start,deg}
    passB_sort<<<NC, 512, 0, stream>>>(pair_buf, starts, sorted_src, meta);

    // 5. gather-sum bf16 rows -> packed bf16 agg (ws)
    gather_kernel<<<NN / 4, 256, 0, stream>>>(
        (const unsigned int*)xb, sorted_src, meta, aggb);

    // 6. MFMA transform + normalize (aggb,xb -> out)
    transform_mfma<<<TBLOCKS, 256, 0, stream>>>(
        out, (const unsigned short*)aggb, xb, wct, Bv, meta);
}